// Round 1
// baseline (125.295 us; speedup 1.0000x reference)
//
#include <hip/hip_runtime.h>
#include <math.h>

#define NT 256

// Strided LDS copy from global
#define CP(dst, src, n) do { for (int i = tid; i < (n); i += NT) (dst)[i] = (src)[i]; } while (0)

// Dense layer over 20 rows: out(20,DOUT) = act(in(20,DIN) @ w(DIN,DOUT) + b)
template<int DIN, int DOUT, bool RELU>
__device__ __forceinline__ void dense20(int tid, const float* __restrict__ in,
                                        const float* __restrict__ w,
                                        const float* __restrict__ bi,
                                        float* __restrict__ out) {
    constexpr int N = 20 * DOUT;
    #pragma unroll
    for (int i0 = 0; i0 < N; i0 += NT) {
        int i = i0 + tid;
        if (i < N) {
            int r = i / DOUT, c = i % DOUT;   // DOUT is 8/16/32 -> shifts
            float acc = bi[c];
            #pragma unroll
            for (int k = 0; k < DIN; ++k)
                acc = fmaf(in[r * DIN + k], w[k * DOUT + c], acc);
            out[i] = RELU ? fmaxf(acc, 0.0f) : acc;
        }
    }
}

__global__ __launch_bounds__(NT)
void fused_net_kernel(const float* __restrict__ inp,
                      const float* __restrict__ h1w, const float* __restrict__ h1b,
                      const float* __restrict__ h2w, const float* __restrict__ h2b,
                      const float* __restrict__ h3w, const float* __restrict__ h3b,
                      const float* __restrict__ d1w, const float* __restrict__ d1b,
                      const float* __restrict__ d2w, const float* __restrict__ d2b,
                      const float* __restrict__ d3w, const float* __restrict__ d3b,
                      const float* __restrict__ g1w, const float* __restrict__ g1b,
                      const float* __restrict__ g2w, const float* __restrict__ g2b,
                      const float* __restrict__ g3w, const float* __restrict__ g3b,
                      const float* __restrict__ fc1w, const float* __restrict__ fc1b,
                      const float* __restrict__ fc2w, const float* __restrict__ fc2b,
                      const float* __restrict__ fc3w, const float* __restrict__ fc3b,
                      const float* __restrict__ fc4w, const float* __restrict__ fc4b,
                      float* __restrict__ out) {
    const int tid = threadIdx.x;

    // ---- LDS mirrors of everything live ----
    __shared__ float s_ni[100];      // (20,5)
    __shared__ float s_valid[20];
    __shared__ float s_summ[400];    // (20,20)
    __shared__ float s_run[20];
    __shared__ float s_back[400];    // (20,20)
    __shared__ float s_h1w[80],  s_h1b[16];
    __shared__ float s_h2w[128], s_h2b[8];
    __shared__ float s_h3w[64],  s_h3b[8];
    __shared__ float s_d1w[208], s_d1b[16];
    __shared__ float s_d2w[128], s_d2b[8];
    __shared__ float s_d3w[64],  s_d3b[8];
    __shared__ float s_g1w[128], s_g1b[16];
    __shared__ float s_g2w[128], s_g2b[8];
    __shared__ float s_g3w[64],  s_g3b[8];
    __shared__ float s_fc1w[928], s_fc1b[32];
    __shared__ float s_fc2w[512], s_fc2b[16];
    __shared__ float s_fc3w[128], s_fc3b[8];
    __shared__ float s_fc4w[8],   s_fc4b[1];
    __shared__ float s_bufA[640];    // ping (max 20x32)
    __shared__ float s_bufB[640];    // pong
    __shared__ float s_gcn[160];     // (20,8)
    __shared__ float s_dag[160];     // (20,8) dag_summary, later fc3 out
    __shared__ float s_glob[8];
    __shared__ float s_logit[20];

    // ---- Phase 0: one burst of independent global->LDS copies ----
    CP(s_ni,    inp,        100);
    CP(s_valid, inp + 100,  20);
    CP(s_summ,  inp + 3480, 400);
    CP(s_run,   inp + 3880, 20);
    CP(s_back,  inp + 3900, 400);
    CP(s_h1w, h1w, 80);   CP(s_h1b, h1b, 16);
    CP(s_h2w, h2w, 128);  CP(s_h2b, h2b, 8);
    CP(s_h3w, h3w, 64);   CP(s_h3b, h3b, 8);
    CP(s_d1w, d1w, 208);  CP(s_d1b, d1b, 16);
    CP(s_d2w, d2w, 128);  CP(s_d2b, d2b, 8);
    CP(s_d3w, d3w, 64);   CP(s_d3b, d3b, 8);
    CP(s_g1w, g1w, 128);  CP(s_g1b, g1b, 16);
    CP(s_g2w, g2w, 128);  CP(s_g2b, g2b, 8);
    CP(s_g3w, g3w, 64);   CP(s_g3b, g3b, 8);
    CP(s_fc1w, fc1w, 928); CP(s_fc1b, fc1b, 32);
    CP(s_fc2w, fc2w, 512); CP(s_fc2b, fc2b, 16);
    CP(s_fc3w, fc3w, 128); CP(s_fc3b, fc3b, 8);
    CP(s_fc4w, fc4w, 8);   CP(s_fc4b, fc4b, 1);
    __syncthreads();

    // ---- GCN head (f-blocks are dead code: multiplied by zeros(20,1)) ----
    dense20<5, 16, true>(tid, s_ni,   s_h1w, s_h1b, s_bufA); __syncthreads();
    dense20<16, 8, true>(tid, s_bufA, s_h2w, s_h2b, s_bufB); __syncthreads();
    dense20<8,  8, true>(tid, s_bufB, s_h3w, s_h3b, s_gcn);  __syncthreads();

    // ---- d1 with fused concat([ni, gcn]) : (20,13)@(13,16) ----
    {
        int i = tid;
        if (i < 320) {
            int r = i >> 4, c = i & 15;
            float acc = s_d1b[c];
            #pragma unroll
            for (int k = 0; k < 5; ++k)
                acc = fmaf(s_ni[r * 5 + k], s_d1w[k * 16 + c], acc);
            #pragma unroll
            for (int k = 0; k < 8; ++k)
                acc = fmaf(s_gcn[r * 8 + k], s_d1w[(5 + k) * 16 + c], acc);
            s_bufA[i] = fmaxf(acc, 0.0f);
        }
        // tid 256..319 handled below via second strided slot
        int j = tid + NT;
        if (j < 320) {
            int r = j >> 4, c = j & 15;
            float acc = s_d1b[c];
            #pragma unroll
            for (int k = 0; k < 5; ++k)
                acc = fmaf(s_ni[r * 5 + k], s_d1w[k * 16 + c], acc);
            #pragma unroll
            for (int k = 0; k < 8; ++k)
                acc = fmaf(s_gcn[r * 8 + k], s_d1w[(5 + k) * 16 + c], acc);
            s_bufA[j] = fmaxf(acc, 0.0f);
        }
    }
    __syncthreads();
    dense20<16, 8, true>(tid, s_bufA, s_d2w, s_d2b, s_bufB); __syncthreads();
    dense20<8,  8, true>(tid, s_bufB, s_d3w, s_d3b, s_bufA); __syncthreads();

    // ---- dag_summary = summ @ s3 : (20,20)@(20,8) ----
    if (tid < 160) {
        int r = tid >> 3, c = tid & 7;
        float acc = 0.0f;
        #pragma unroll
        for (int k = 0; k < 20; ++k)
            acc = fmaf(s_summ[r * 20 + k], s_bufA[k * 8 + c], acc);
        s_dag[tid] = acc;
    }
    __syncthreads();

    // ---- g-chain on dag_summary ----
    dense20<8, 16, true>(tid, s_dag,  s_g1w, s_g1b, s_bufA); __syncthreads();
    dense20<16, 8, true>(tid, s_bufA, s_g2w, s_g2b, s_bufB); __syncthreads();
    dense20<8,  8, true>(tid, s_bufB, s_g3w, s_g3b, s_bufA); __syncthreads();

    // ---- dag_ext = backmap @ dag (160 outs)  ||  glob = running @ g3out (8 outs) ----
    if (tid < 160) {
        int r = tid >> 3, c = tid & 7;
        float acc = 0.0f;
        #pragma unroll
        for (int k = 0; k < 20; ++k)
            acc = fmaf(s_back[r * 20 + k], s_dag[k * 8 + c], acc);
        s_bufB[tid] = acc;
    } else if (tid < 168) {
        int c = tid - 160;
        float acc = 0.0f;
        #pragma unroll
        for (int k = 0; k < 20; ++k)
            acc = fmaf(s_run[k], s_bufA[k * 8 + c], acc);
        s_glob[c] = acc;
    }
    __syncthreads();

    // ---- fc1 with fused concat([ni, gcn, dag_ext, glob]) : (20,29)@(29,32) ----
    #pragma unroll
    for (int i0 = 0; i0 < 640; i0 += NT) {
        int i = i0 + tid;
        if (i < 640) {
            int r = i >> 5, c = i & 31;
            float acc = s_fc1b[c];
            #pragma unroll
            for (int k = 0; k < 5; ++k)
                acc = fmaf(s_ni[r * 5 + k], s_fc1w[k * 32 + c], acc);
            #pragma unroll
            for (int k = 0; k < 8; ++k)
                acc = fmaf(s_gcn[r * 8 + k], s_fc1w[(5 + k) * 32 + c], acc);
            #pragma unroll
            for (int k = 0; k < 8; ++k)
                acc = fmaf(s_bufB[r * 8 + k], s_fc1w[(13 + k) * 32 + c], acc);
            #pragma unroll
            for (int k = 0; k < 8; ++k)
                acc = fmaf(s_glob[k], s_fc1w[(21 + k) * 32 + c], acc);
            s_bufA[i] = fmaxf(acc, 0.0f);
        }
    }
    __syncthreads();
    dense20<32, 16, true>(tid, s_bufA, s_fc2w, s_fc2b, s_bufB); __syncthreads();
    dense20<16, 8, true>(tid, s_bufB, s_fc3w, s_fc3b, s_dag);   __syncthreads();

    // ---- fc4 + valid mask -> logits ----
    if (tid < 20) {
        float acc = s_fc4b[0];
        #pragma unroll
        for (int k = 0; k < 8; ++k)
            acc = fmaf(s_dag[tid * 8 + k], s_fc4w[k], acc);
        s_logit[tid] = acc + (s_valid[tid] - 1.0f) * 10000.0f;
    }
    __syncthreads();

    // ---- softmax over 20 (serial on thread 0, trivial) ----
    if (tid == 0) {
        float m = s_logit[0];
        #pragma unroll
        for (int r = 1; r < 20; ++r) m = fmaxf(m, s_logit[r]);
        float e[20];
        float sum = 0.0f;
        #pragma unroll
        for (int r = 0; r < 20; ++r) { e[r] = __expf(s_logit[r] - m); sum += e[r]; }
        float inv = 1.0f / sum;
        #pragma unroll
        for (int r = 0; r < 20; ++r) out[r] = e[r] * inv;
    }
}

extern "C" void kernel_launch(void* const* d_in, const int* in_sizes, int n_in,
                              void* d_out, int out_size, void* d_ws, size_t ws_size,
                              hipStream_t stream) {
    const float* inp = (const float*)d_in[0];
    // dict order: input, then (w,b) for h1,h2,h3, f1,f2,f3, d1,d2,d3, g1,g2,g3, fc1..fc4
    const float* h1w = (const float*)d_in[1];  const float* h1b = (const float*)d_in[2];
    const float* h2w = (const float*)d_in[3];  const float* h2b = (const float*)d_in[4];
    const float* h3w = (const float*)d_in[5];  const float* h3b = (const float*)d_in[6];
    // f1..f3 (indices 7..12) are dead code: outputs multiplied by zeros(20,1)
    const float* d1w = (const float*)d_in[13]; const float* d1b = (const float*)d_in[14];
    const float* d2w = (const float*)d_in[15]; const float* d2b = (const float*)d_in[16];
    const float* d3w = (const float*)d_in[17]; const float* d3b = (const float*)d_in[18];
    const float* g1w = (const float*)d_in[19]; const float* g1b = (const float*)d_in[20];
    const float* g2w = (const float*)d_in[21]; const float* g2b = (const float*)d_in[22];
    const float* g3w = (const float*)d_in[23]; const float* g3b = (const float*)d_in[24];
    const float* fc1w = (const float*)d_in[25]; const float* fc1b = (const float*)d_in[26];
    const float* fc2w = (const float*)d_in[27]; const float* fc2b = (const float*)d_in[28];
    const float* fc3w = (const float*)d_in[29]; const float* fc3b = (const float*)d_in[30];
    const float* fc4w = (const float*)d_in[31]; const float* fc4b = (const float*)d_in[32];
    float* out = (float*)d_out;

    fused_net_kernel<<<1, NT, 0, stream>>>(inp,
        h1w, h1b, h2w, h2b, h3w, h3b,
        d1w, d1b, d2w, d2b, d3w, d3b,
        g1w, g1b, g2w, g2b, g3w, g3b,
        fc1w, fc1b, fc2w, fc2b, fc3w, fc3b, fc4w, fc4b,
        out);
}